// Round 3
// baseline (4288.799 us; speedup 1.0000x reference)
//
#include <hip/hip_runtime.h>
#include <hip/hip_bf16.h>

// Problem constants
#define NTOT 65536      // B*N
#define NB   16384      // N per batch
#define MB   4096       // M per batch (queries/batch)
#define NQ   16384      // total queries
#define KNN  20
#define CKEEP 32        // kept candidates before exact re-rank (margin over 20)
#define CAP  160        // per-query candidate buffer capacity (u32)
#define TRIG 33         // compaction trigger (post-compact cnt=32 < TRIG)
#define KFT_ROWS 68     // 67 dims + squared-norm row

// ws layout (floats): kfT[68][65536], then nbr int[NQ*KNN]
#define NBR_OFF (KFT_ROWS * NTOT)

// ---------------------------------------------------------------------------
// k_prep: per-node kf = [s(16), R^T v (48), pos(3)], plus |kf|^2, stored
// dim-major: kfT[d][node]  (coalesced across nodes for every d).
// ---------------------------------------------------------------------------
__global__ __launch_bounds__(256) void k_prep(const float* __restrict__ x,
        const float* __restrict__ pos, const float* __restrict__ lfr,
        float* __restrict__ kfT){
  int n = blockIdx.x * 256 + threadIdx.x;
  const float* xr = x + n * 64;
  float R[9];
  #pragma unroll
  for (int j = 0; j < 9; j++) R[j] = lfr[n * 9 + j];
  float c[67];
  #pragma unroll
  for (int i = 0; i < 16; i++) c[i] = xr[i];
  #pragma unroll
  for (int k = 0; k < 16; k++){
    float v0 = xr[16 + 3*k], v1 = xr[17 + 3*k], v2 = xr[18 + 3*k];
    #pragma unroll
    for (int a = 0; a < 3; a++)
      c[16 + 3*k + a] = R[a] * v0 + R[3 + a] * v1 + R[6 + a] * v2;  // R^T v
  }
  #pragma unroll
  for (int a = 0; a < 3; a++) c[64 + a] = pos[n * 3 + a];
  float sq = 0.f;
  #pragma unroll
  for (int d = 0; d < 67; d++) sq += c[d] * c[d];
  #pragma unroll
  for (int d = 0; d < 67; d++) kfT[d * NTOT + n] = c[d];
  kfT[67 * NTOT + n] = sq;
}

// ---------------------------------------------------------------------------
// k_knn: fused distance + streaming top-K.
// 64 queries/block, key tiles of 256, 8q x 8k register micro-tile.
// Candidates packed as u32 = round(d2) upper-18-bits | key_idx(14b); kept set
// of 32 re-ranked exactly in fp64 (kf rebuilt from inputs) -> true top-20.
// ---------------------------------------------------------------------------
__device__ __forceinline__ void compact32(unsigned* bq, int* cq, float* tq){
  int c = *cq;
  int m = c < CKEEP ? c : CKEEP;
  for (int s = 0; s < m; s++){
    unsigned best = bq[s]; int bi = s;
    for (int t = s + 1; t < c; t++){ unsigned v = bq[t]; if (v < best){ best = v; bi = t; } }
    bq[bi] = bq[s]; bq[s] = best;
  }
  *cq = m;
  if (m == CKEEP) *tq = __uint_as_float(bq[CKEEP - 1] & 0xFFFFC000u);
}

__global__ __launch_bounds__(256, 1) void k_knn(const float* __restrict__ kfT,
    const float* __restrict__ x, const float* __restrict__ pos,
    const float* __restrict__ lfr, int* __restrict__ nbr){
  __shared__ float qsT[KFT_ROWS][64];                               // 17408 B
  __shared__ __attribute__((aligned(16))) float ksT[KFT_ROWS][256]; // 69632 B (reused as fp64 re-rank scratch)
  __shared__ unsigned buf[64][CAP];                                 // 40960 B
  __shared__ int cnt[64];
  __shared__ float tau[64];

  int tid = threadIdx.x;
  int blk = blockIdx.x;
  // XCD-friendly swizzle: 2 consecutive-XCD slots per batch
  int b = (blk & 7) >> 1;
  int w = ((blk >> 3) << 1) | (blk & 1);   // 0..63 within batch
  int bbase = b << 14;                     // b*16384
  int q0 = w << 6;                         // within-batch query base (w*64)

  if (tid < 64){ cnt[tid] = 0; tau[tid] = 3.0e38f; }
  // stage queries (node = bbase + 4*(q0+i)), rows 0..67
  for (int p = tid; p < KFT_ROWS * 64; p += 256){
    int d = p >> 6, i = p & 63;
    qsT[d][i] = kfT[d * NTOT + bbase + ((q0 + i) << 2)];
  }
  __syncthreads();

  int qg = tid >> 5, kg = tid & 31;
  float qsq[8];
  #pragma unroll
  for (int i = 0; i < 8; i++) qsq[i] = qsT[67][qg * 8 + i];

  for (int tile = 0; tile < 64; ++tile){
    __syncthreads();   // previous tile's reads of ksT complete
    int kbase = tile << 8;
    // stage 256 keys dim-major: 68*64 float4s, coalesced global, conflict-free LDS
    for (int p = tid; p < KFT_ROWS * 64; p += 256){
      int d = p >> 6, k4 = (p & 63) << 2;
      *(float4*)&ksT[d][k4] = *(const float4*)&kfT[d * NTOT + bbase + kbase + k4];
    }
    __syncthreads();

    float acc[8][8];
    #pragma unroll
    for (int i = 0; i < 8; i++)
      #pragma unroll
      for (int j = 0; j < 8; j++) acc[i][j] = 0.f;

    for (int d = 0; d < 67; ++d){
      float4 ka = *(float4*)&ksT[d][kg << 2];
      float4 kb = *(float4*)&ksT[d][128 + (kg << 2)];
      float4 qa = *(float4*)&qsT[d][qg << 3];
      float4 qb = *(float4*)&qsT[d][(qg << 3) + 4];
      float qv[8] = {qa.x, qa.y, qa.z, qa.w, qb.x, qb.y, qb.z, qb.w};
      float kv[8] = {ka.x, ka.y, ka.z, ka.w, kb.x, kb.y, kb.z, kb.w};
      #pragma unroll
      for (int i = 0; i < 8; i++)
        #pragma unroll
        for (int j = 0; j < 8; j++)
          acc[i][j] += qv[i] * kv[j];
    }

    float ksq[8];
    #pragma unroll
    for (int j = 0; j < 4; j++){
      ksq[j]     = ksT[67][(kg << 2) + j];
      ksq[4 + j] = ksT[67][128 + (kg << 2) + j];
    }

    // phase A: keys [kbase+4kg .. +3]
    #pragma unroll
    for (int i = 0; i < 8; i++){
      int q = (qg << 3) + i;
      float tq = tau[q];
      #pragma unroll
      for (int j = 0; j < 4; j++){
        float d2 = fmaxf(qsq[i] + ksq[j] - 2.f * acc[i][j], 0.f);
        if (d2 < tq){
          int p = atomicAdd(&cnt[q], 1);
          buf[q][p] = ((__float_as_uint(d2) + 0x2000u) & 0xFFFFC000u) | (unsigned)(kbase + (kg << 2) + j);
        }
      }
    }
    __syncthreads();
    if (tid < 64 && cnt[tid] >= TRIG) compact32(buf[tid], &cnt[tid], &tau[tid]);
    __syncthreads();
    // phase B: keys [kbase+128+4kg .. +3]
    #pragma unroll
    for (int i = 0; i < 8; i++){
      int q = (qg << 3) + i;
      float tq = tau[q];
      #pragma unroll
      for (int j = 0; j < 4; j++){
        float d2 = fmaxf(qsq[i] + ksq[4 + j] - 2.f * acc[i][4 + j], 0.f);
        if (d2 < tq){
          int p = atomicAdd(&cnt[q], 1);
          buf[q][p] = ((__float_as_uint(d2) + 0x2000u) & 0xFFFFC000u) | (unsigned)(kbase + 128 + (kg << 2) + j);
        }
      }
    }
    __syncthreads();
    if (tid < 64 && cnt[tid] >= TRIG) compact32(buf[tid], &cnt[tid], &tau[tid]);
  }
  __syncthreads();
  if (tid < 64) compact32(buf[tid], &cnt[tid], &tau[tid]);  // final: sorted kept-32
  __syncthreads();

  // ---- exact fp64 re-rank of the 32 survivors (kf rebuilt from raw inputs) ----
  // LDS overlay on ksT: qkf double[64][67] | rrD double[64][32] | rrI int[64][32]
  double* qkf = (double*)&ksT[0][0];
  double* rrD = qkf + 64 * 67;
  int*    rrI = (int*)(rrD + 64 * CKEEP);

  {  // rebuild query kf in fp64
    int t4 = tid & 3, q = tid >> 2;
    int node = bbase + ((q0 + q) << 2);
    const float* xr = x + node * 64;
    for (int dd = t4; dd < 67; dd += 4){
      double val;
      if (dd < 16) val = (double)xr[dd];
      else if (dd < 64){
        int r = dd - 16; int k = r / 3; int a = r - 3 * k;
        val = (double)lfr[node*9 + a]     * (double)xr[16 + 3*k]
            + (double)lfr[node*9 + 3 + a] * (double)xr[17 + 3*k]
            + (double)lfr[node*9 + 6 + a] * (double)xr[18 + 3*k];
      } else val = (double)pos[node*3 + (dd - 64)];
      qkf[q * 67 + dd] = val;
    }
  }
  __syncthreads();
  {  // candidate d2 in fp64
    int t4 = tid & 3, q = tid >> 2;
    for (int j = t4; j < CKEEP; j += 4){
      int idx = (int)(buf[q][j] & 0x3FFFu);
      int node = bbase + idx;
      const float* xr = x + node * 64;
      double R[9];
      #pragma unroll
      for (int t = 0; t < 9; t++) R[t] = (double)lfr[node * 9 + t];
      double d2 = 0.0;
      #pragma unroll
      for (int dd = 0; dd < 16; dd++){ double t = (double)xr[dd] - qkf[q*67 + dd]; d2 += t * t; }
      #pragma unroll
      for (int k = 0; k < 16; k++){
        double v0 = xr[16 + 3*k], v1 = xr[17 + 3*k], v2 = xr[18 + 3*k];
        #pragma unroll
        for (int a = 0; a < 3; a++){
          double val = R[a] * v0 + R[3 + a] * v1 + R[6 + a] * v2;
          double t = val - qkf[q*67 + 16 + 3*k + a]; d2 += t * t;
        }
      }
      #pragma unroll
      for (int a = 0; a < 3; a++){ double t = (double)pos[node*3 + a] - qkf[q*67 + 64 + a]; d2 += t * t; }
      rrD[q * CKEEP + j] = d2; rrI[q * CKEEP + j] = idx;
    }
  }
  __syncthreads();
  if (tid < 64){
    int qq = tid;
    int qid = (b << 12) + q0 + qq;   // global query id
    #pragma unroll 1
    for (int s = 0; s < KNN; s++){
      double best = rrD[qq * CKEEP + s]; int bi = s;
      for (int t = s + 1; t < CKEEP; t++){
        double v = rrD[qq * CKEEP + t]; if (v < best){ best = v; bi = t; }
      }
      double tv = rrD[qq * CKEEP + bi]; rrD[qq * CKEEP + bi] = rrD[qq * CKEEP + s]; rrD[qq * CKEEP + s] = tv;
      int ti = rrI[qq * CKEEP + bi]; rrI[qq * CKEEP + bi] = rrI[qq * CKEEP + s]; rrI[qq * CKEEP + s] = ti;
      nbr[qid * KNN + s] = bbase + rrI[qq * CKEEP + s];
    }
  }
}

// ---------------------------------------------------------------------------
// k_mlp: 2 queries/block (40 edges). Gather x_src, build h=[x_dst, rel_local],
// relu(h@W1+b1)@W2, max over edges, +b2, fp32 store.
// Micro-tile: 20 edges x 1 output per thread; h/a1 LDS reads are wave-broadcast.
// ---------------------------------------------------------------------------
__global__ __launch_bounds__(256) void k_mlp(const float* __restrict__ x,
    const float* __restrict__ lfr, const int* __restrict__ nbr,
    const float* __restrict__ W1, const float* __restrict__ b1,
    const float* __restrict__ W2, const float* __restrict__ b2,
    float* __restrict__ out){
  __shared__ float xs[40][64];
  __shared__ float h[40][128];
  __shared__ float a1[40][128];
  __shared__ float xdL[2][64];
  __shared__ float lfL[2][9];
  __shared__ int nbrL[40];

  int tid = threadIdx.x;
  int qid0 = blockIdx.x * 2;
  if (tid < 128){
    int ql = tid >> 6, d = tid & 63;
    int qid = qid0 + ql;
    int node = ((qid >> 12) << 14) + ((qid & 4095) << 2);
    xdL[ql][d] = x[node * 64 + d];
  } else if (tid < 146){
    int t = tid - 128; int ql = t / 9, j = t - 9 * ql;
    int qid = qid0 + ql;
    int node = ((qid >> 12) << 14) + ((qid & 4095) << 2);
    lfL[ql][j] = lfr[node * 9 + j];
  } else if (tid < 186){
    int t = tid - 146; int ql = t / 20, j = t - 20 * ql;
    nbrL[t] = nbr[(qid0 + ql) * 20 + j];
  }
  __syncthreads();
  // gather x_src (coalesced 64-float rows)
  #pragma unroll 1
  for (int p = 0; p < 10; p++){
    int e = (tid >> 6) + (p << 2), d = tid & 63;
    xs[e][d] = x[nbrL[e] * 64 + d];
  }
  __syncthreads();
  // build h: [0..63]=x_dst, [64..79]=rel scalars, [80..127]=R_dst @ rel_vec
  {
    int d = tid & 127;
    int cls, kk = 0, aa = 0;
    if (d < 64) cls = 0;
    else { int dd = d - 64;
      if (dd < 16) cls = 1;
      else { cls = 2; int r = dd - 16; kk = (r * 21846) >> 16; aa = r - 3 * kk; } }
    #pragma unroll 1
    for (int p = 0; p < 20; p++){
      int e = (tid >> 7) + (p << 1);
      int ql = (e >= 20) ? 1 : 0;
      float v;
      if (cls == 0) v = xdL[ql][d];
      else if (cls == 1) v = xs[e][d - 64] - xdL[ql][d - 64];
      else {
        int base = 16 + 3 * kk;
        float u0 = xs[e][base]     - xdL[ql][base];
        float u1 = xs[e][base + 1] - xdL[ql][base + 1];
        float u2 = xs[e][base + 2] - xdL[ql][base + 2];
        v = lfL[ql][aa * 3] * u0 + lfL[ql][aa * 3 + 1] * u1 + lfL[ql][aa * 3 + 2] * u2;
      }
      h[e][d] = v;
    }
  }
  __syncthreads();
  int eg = tid >> 7, og = tid & 127;
  // layer 1
  {
    float acc1[20];
    float bv = b1[og];
    #pragma unroll
    for (int i = 0; i < 20; i++) acc1[i] = bv;
    for (int d0 = 0; d0 < 128; d0 += 4){
      float w0 = W1[(d0 + 0) * 128 + og];
      float w1 = W1[(d0 + 1) * 128 + og];
      float w2 = W1[(d0 + 2) * 128 + og];
      float w3 = W1[(d0 + 3) * 128 + og];
      #pragma unroll
      for (int i = 0; i < 20; i++){
        float4 hv = *(float4*)&h[eg * 20 + i][d0];
        acc1[i] += hv.x * w0 + hv.y * w1 + hv.z * w2 + hv.w * w3;
      }
    }
    #pragma unroll
    for (int i = 0; i < 20; i++) a1[eg * 20 + i][og] = fmaxf(acc1[i], 0.f);
  }
  __syncthreads();
  // layer 2 + max over edges
  {
    float acc2[20];
    #pragma unroll
    for (int i = 0; i < 20; i++) acc2[i] = 0.f;
    for (int d0 = 0; d0 < 128; d0 += 4){
      float w0 = W2[(d0 + 0) * 128 + og];
      float w1 = W2[(d0 + 1) * 128 + og];
      float w2 = W2[(d0 + 2) * 128 + og];
      float w3 = W2[(d0 + 3) * 128 + og];
      #pragma unroll
      for (int i = 0; i < 20; i++){
        float4 av = *(float4*)&a1[eg * 20 + i][d0];
        acc2[i] += av.x * w0 + av.y * w1 + av.z * w2 + av.w * w3;
      }
    }
    float m = -3.0e38f;
    #pragma unroll
    for (int i = 0; i < 20; i++) m = fmaxf(m, acc2[i]);
    m += b2[og];
    out[(qid0 + eg) * 128 + og] = m;
  }
}

// ---------------------------------------------------------------------------
// k_tail: pos[idx], batch[idx], lframes[idx] as fp32 at flat offsets.
// ---------------------------------------------------------------------------
__global__ __launch_bounds__(256) void k_tail(const float* __restrict__ pos,
    const float* __restrict__ lfr, float* __restrict__ out){
  int q = blockIdx.x * 256 + threadIdx.x;   // 0..16383
  int b = q >> 12;
  int node = (b << 14) + ((q & 4095) << 2);
  float* o_pos = out + 2097152;    // 16384*128
  float* o_bat = out + 2146304;    // + 16384*3
  float* o_lf  = out + 2162688;    // + 16384
  #pragma unroll
  for (int j = 0; j < 3; j++) o_pos[q * 3 + j] = pos[node * 3 + j];
  o_bat[q] = (float)b;
  #pragma unroll
  for (int j = 0; j < 9; j++) o_lf[q * 9 + j] = lfr[node * 9 + j];
}

extern "C" void kernel_launch(void* const* d_in, const int* in_sizes, int n_in,
                              void* d_out, int out_size, void* d_ws, size_t ws_size,
                              hipStream_t stream){
  const float* x   = (const float*)d_in[0];
  const float* pos = (const float*)d_in[1];
  const float* lfr = (const float*)d_in[2];
  // d_in[3] = batch (recomputed analytically)
  const float* W1  = (const float*)d_in[4];
  const float* b1  = (const float*)d_in[5];
  const float* W2  = (const float*)d_in[6];
  const float* b2  = (const float*)d_in[7];

  float* kfT = (float*)d_ws;                 // 68*65536 floats = 17.8 MB
  int*   nbr = (int*)d_ws + NBR_OFF;         // 16384*20 ints
  float* out = (float*)d_out;

  hipLaunchKernelGGL(k_prep, dim3(256),  dim3(256), 0, stream, x, pos, lfr, kfT);
  hipLaunchKernelGGL(k_knn,  dim3(256),  dim3(256), 0, stream, kfT, x, pos, lfr, nbr);
  hipLaunchKernelGGL(k_mlp,  dim3(8192), dim3(256), 0, stream, x, lfr, nbr, W1, b1, W2, b2, out);
  hipLaunchKernelGGL(k_tail, dim3(64),   dim3(256), 0, stream, pos, lfr, out);
}

// Round 4
// 1864.604 us; speedup vs baseline: 2.3001x; 2.3001x over previous
//
#include <hip/hip_runtime.h>
#include <hip/hip_bf16.h>

// Problem constants
#define NTOT 65536      // B*N
#define NB   16384      // N per batch
#define MB   4096       // M per batch (queries/batch)
#define NQ   16384      // total queries
#define KNN  20
#define CKEEP 32        // kept candidates for exact re-rank (margin over 20)
#define CAPB 224        // candidate buffer rows (headroom 128 over 96)
#define BPAD 65         // padded row width (64 queries + 1) -> bank varies with row
#define HEADROOM 96     // compact when cnt > HEADROOM
#define KFT_ROWS 68     // 67 dims + squared-norm row

// ws layout (floats): kfT[68][65536], then nbr int[NQ*KNN]
#define NBR_OFF (KFT_ROWS * NTOT)

// ---------------------------------------------------------------------------
// k_prep: per-node kf = [s(16), R^T v (48), pos(3)], plus |kf|^2, stored
// dim-major: kfT[d][node]  (coalesced across nodes for every d).
// ---------------------------------------------------------------------------
__global__ __launch_bounds__(256) void k_prep(const float* __restrict__ x,
        const float* __restrict__ pos, const float* __restrict__ lfr,
        float* __restrict__ kfT){
  int n = blockIdx.x * 256 + threadIdx.x;
  const float* xr = x + n * 64;
  float R[9];
  #pragma unroll
  for (int j = 0; j < 9; j++) R[j] = lfr[n * 9 + j];
  float c[67];
  #pragma unroll
  for (int i = 0; i < 16; i++) c[i] = xr[i];
  #pragma unroll
  for (int k = 0; k < 16; k++){
    float v0 = xr[16 + 3*k], v1 = xr[17 + 3*k], v2 = xr[18 + 3*k];
    #pragma unroll
    for (int a = 0; a < 3; a++)
      c[16 + 3*k + a] = R[a] * v0 + R[3 + a] * v1 + R[6 + a] * v2;  // R^T v
  }
  #pragma unroll
  for (int a = 0; a < 3; a++) c[64 + a] = pos[n * 3 + a];
  float sq = 0.f;
  #pragma unroll
  for (int d = 0; d < 67; d++) sq += c[d] * c[d];
  #pragma unroll
  for (int d = 0; d < 67; d++) kfT[d * NTOT + n] = c[d];
  kfT[67 * NTOT + n] = sq;
}

// ---------------------------------------------------------------------------
// k_knn: fused distance + streaming top-K.
// 64 queries/block, key tiles of 256, 8q x 8k register micro-tile.
// Candidates packed u32 = round(d2) upper-18-bits | key_idx(14b), stored
// TRANSPOSED buf[p][q] (padded stride 65 -> conflict-free scans).
// Compaction: block-uniform trigger (cnt>96), cooperative 4-lanes/query
// selection of best-32, tau = 32nd best. Final 32 re-ranked in fp64.
// ---------------------------------------------------------------------------
__device__ __forceinline__ void coop_compact(unsigned (*buf)[BPAD],
    unsigned (*srt)[BPAD], int* cnt, float* tau, int tid){
  int q = tid >> 2, s = tid & 3;
  int cn = cnt[q];
  #pragma unroll 1
  for (int r = 0; r < 32; r++){
    unsigned best = 0xFFFFFFFFu; int bj = -1;
    for (int j = s; j < cn; j += 4){
      unsigned v = buf[j][q];
      if (v < best){ best = v; bj = j; }
    }
    #pragma unroll
    for (int off = 1; off < 4; off <<= 1){
      unsigned ov = (unsigned)__shfl_xor((int)best, off, 64);
      int      oj = __shfl_xor(bj, off, 64);
      if (ov < best){ best = ov; bj = oj; }
    }
    if (bj >= 0 && s == (bj & 3)) buf[bj][q] = 0xFFFFFFFFu;  // extract
    if (s == 0) srt[r][q] = best;
    __syncthreads();
  }
  for (int r = s; r < 32; r += 4) buf[r][q] = srt[r][q];
  if (s == 0){ cnt[q] = 32; tau[q] = __uint_as_float(srt[31][q] & 0xFFFFC000u); }
  __syncthreads();
}

__global__ __launch_bounds__(256, 1) void k_knn(const float* __restrict__ kfT,
    const float* __restrict__ x, const float* __restrict__ pos,
    const float* __restrict__ lfr, int* __restrict__ nbr){
  __shared__ __attribute__((aligned(16))) float qsT[KFT_ROWS][64];  // 17408 B
  __shared__ __attribute__((aligned(16))) float ksT[KFT_ROWS][256]; // 69632 B (reused as fp64 re-rank scratch)
  __shared__ unsigned buf[CAPB][BPAD];                              // 58240 B
  __shared__ unsigned srt[32][BPAD];                                // 8320 B
  __shared__ int cnt[64];
  __shared__ float tau[64];
  __shared__ int flagS;

  int tid = threadIdx.x;
  int blk = blockIdx.x;
  // XCD-friendly swizzle: 2 consecutive-XCD slots per batch
  int b = (blk & 7) >> 1;
  int w = ((blk >> 3) << 1) | (blk & 1);   // 0..63 within batch
  int bbase = b << 14;                     // b*16384
  int q0 = w << 6;                         // within-batch query base (w*64)

  if (tid < 64){ cnt[tid] = 0; tau[tid] = 3.0e38f; }
  if (tid == 0) flagS = 0;
  // stage queries (node = bbase + 4*(q0+i)), rows 0..67
  for (int p = tid; p < KFT_ROWS * 64; p += 256){
    int d = p >> 6, i = p & 63;
    qsT[d][i] = kfT[d * NTOT + bbase + ((q0 + i) << 2)];
  }
  __syncthreads();

  int qg = tid >> 5, kg = tid & 31;
  float qsq[8];
  #pragma unroll
  for (int i = 0; i < 8; i++) qsq[i] = qsT[67][qg * 8 + i];

  for (int tile = 0; tile < 64; ++tile){
    __syncthreads();   // previous tile's reads of ksT complete
    int kbase = tile << 8;
    // stage 256 keys dim-major: 68*64 float4s, coalesced global, conflict-free LDS
    for (int p = tid; p < KFT_ROWS * 64; p += 256){
      int d = p >> 6, k4 = (p & 63) << 2;
      *(float4*)&ksT[d][k4] = *(const float4*)&kfT[d * NTOT + bbase + kbase + k4];
    }
    __syncthreads();

    float acc[8][8];
    #pragma unroll
    for (int i = 0; i < 8; i++)
      #pragma unroll
      for (int j = 0; j < 8; j++) acc[i][j] = 0.f;

    for (int d = 0; d < 67; ++d){
      float4 ka = *(float4*)&ksT[d][kg << 2];
      float4 kb = *(float4*)&ksT[d][128 + (kg << 2)];
      float4 qa = *(float4*)&qsT[d][qg << 3];
      float4 qb = *(float4*)&qsT[d][(qg << 3) + 4];
      float qv[8] = {qa.x, qa.y, qa.z, qa.w, qb.x, qb.y, qb.z, qb.w};
      float kv[8] = {ka.x, ka.y, ka.z, ka.w, kb.x, kb.y, kb.z, kb.w};
      #pragma unroll
      for (int i = 0; i < 8; i++)
        #pragma unroll
        for (int j = 0; j < 8; j++)
          acc[i][j] += qv[i] * kv[j];
    }

    float ksq[8];
    #pragma unroll
    for (int j = 0; j < 4; j++){
      ksq[j]     = ksT[67][(kg << 2) + j];
      ksq[4 + j] = ksT[67][128 + (kg << 2) + j];
    }

    // phase A: keys [kbase+4kg .. +3]
    #pragma unroll
    for (int i = 0; i < 8; i++){
      int q = (qg << 3) + i;
      float tq = tau[q];
      #pragma unroll
      for (int j = 0; j < 4; j++){
        float d2 = fmaxf(qsq[i] + ksq[j] - 2.f * acc[i][j], 0.f);
        if (d2 < tq){
          int p = atomicAdd(&cnt[q], 1);
          buf[p][q] = ((__float_as_uint(d2) + 0x2000u) & 0xFFFFC000u) | (unsigned)(kbase + (kg << 2) + j);
        }
      }
    }
    __syncthreads();
    if (tid < 64 && cnt[tid] > HEADROOM) flagS = 1;
    __syncthreads();
    if (flagS){
      coop_compact(buf, srt, cnt, tau, tid);
      if (tid == 0) flagS = 0;
    }
    // phase B: keys [kbase+128+4kg .. +3]
    #pragma unroll
    for (int i = 0; i < 8; i++){
      int q = (qg << 3) + i;
      float tq = tau[q];
      #pragma unroll
      for (int j = 0; j < 4; j++){
        float d2 = fmaxf(qsq[i] + ksq[4 + j] - 2.f * acc[i][4 + j], 0.f);
        if (d2 < tq){
          int p = atomicAdd(&cnt[q], 1);
          buf[p][q] = ((__float_as_uint(d2) + 0x2000u) & 0xFFFFC000u) | (unsigned)(kbase + 128 + (kg << 2) + j);
        }
      }
    }
    __syncthreads();
    if (tid < 64 && cnt[tid] > HEADROOM) flagS = 1;
    __syncthreads();
    if (flagS){
      coop_compact(buf, srt, cnt, tau, tid);
      if (tid == 0) flagS = 0;
    }
  }
  __syncthreads();
  coop_compact(buf, srt, cnt, tau, tid);   // final: buf rows 0..31 = best-32
  __syncthreads();

  // ---- exact fp64 re-rank of the 32 survivors (kf rebuilt from raw inputs) ----
  // LDS overlay on ksT: qkf double[64][67] | rrD double[64][32] | rrI int[64][32]
  double* qkf = (double*)&ksT[0][0];
  double* rrD = qkf + 64 * 67;
  int*    rrI = (int*)(rrD + 64 * CKEEP);

  {  // rebuild query kf in fp64
    int t4 = tid & 3, q = tid >> 2;
    int node = bbase + ((q0 + q) << 2);
    const float* xr = x + node * 64;
    for (int dd = t4; dd < 67; dd += 4){
      double val;
      if (dd < 16) val = (double)xr[dd];
      else if (dd < 64){
        int r = dd - 16; int k = r / 3; int a = r - 3 * k;
        val = (double)lfr[node*9 + a]     * (double)xr[16 + 3*k]
            + (double)lfr[node*9 + 3 + a] * (double)xr[17 + 3*k]
            + (double)lfr[node*9 + 6 + a] * (double)xr[18 + 3*k];
      } else val = (double)pos[node*3 + (dd - 64)];
      qkf[q * 67 + dd] = val;
    }
  }
  __syncthreads();
  {  // candidate d2 in fp64
    int t4 = tid & 3, q = tid >> 2;
    for (int j = t4; j < CKEEP; j += 4){
      int idx = (int)(buf[j][q] & 0x3FFFu);
      int node = bbase + idx;
      const float* xr = x + node * 64;
      double R[9];
      #pragma unroll
      for (int t = 0; t < 9; t++) R[t] = (double)lfr[node * 9 + t];
      double d2 = 0.0;
      #pragma unroll
      for (int dd = 0; dd < 16; dd++){ double t = (double)xr[dd] - qkf[q*67 + dd]; d2 += t * t; }
      #pragma unroll
      for (int k = 0; k < 16; k++){
        double v0 = xr[16 + 3*k], v1 = xr[17 + 3*k], v2 = xr[18 + 3*k];
        #pragma unroll
        for (int a = 0; a < 3; a++){
          double val = R[a] * v0 + R[3 + a] * v1 + R[6 + a] * v2;
          double t = val - qkf[q*67 + 16 + 3*k + a]; d2 += t * t;
        }
      }
      #pragma unroll
      for (int a = 0; a < 3; a++){ double t = (double)pos[node*3 + a] - qkf[q*67 + 64 + a]; d2 += t * t; }
      rrD[q * CKEEP + j] = d2; rrI[q * CKEEP + j] = idx;
    }
  }
  __syncthreads();
  if (tid < 64){
    int qq = tid;
    int qid = (b << 12) + q0 + qq;   // global query id
    #pragma unroll 1
    for (int s = 0; s < KNN; s++){
      double best = rrD[qq * CKEEP + s]; int bi = s;
      for (int t = s + 1; t < CKEEP; t++){
        double v = rrD[qq * CKEEP + t]; if (v < best){ best = v; bi = t; }
      }
      double tv = rrD[qq * CKEEP + bi]; rrD[qq * CKEEP + bi] = rrD[qq * CKEEP + s]; rrD[qq * CKEEP + s] = tv;
      int ti = rrI[qq * CKEEP + bi]; rrI[qq * CKEEP + bi] = rrI[qq * CKEEP + s]; rrI[qq * CKEEP + s] = ti;
      nbr[qid * KNN + s] = bbase + rrI[qq * CKEEP + s];
    }
  }
}

// ---------------------------------------------------------------------------
// k_mlp: 2 queries/block (40 edges). Gather x_src, build h=[x_dst, rel_local],
// relu(h@W1+b1)@W2, max over edges, +b2, fp32 store.
// Micro-tile: 20 edges x 1 output per thread; h/a1 LDS reads are wave-broadcast.
// ---------------------------------------------------------------------------
__global__ __launch_bounds__(256) void k_mlp(const float* __restrict__ x,
    const float* __restrict__ lfr, const int* __restrict__ nbr,
    const float* __restrict__ W1, const float* __restrict__ b1,
    const float* __restrict__ W2, const float* __restrict__ b2,
    float* __restrict__ out){
  __shared__ float xs[40][64];
  __shared__ float h[40][128];
  __shared__ float a1[40][128];
  __shared__ float xdL[2][64];
  __shared__ float lfL[2][9];
  __shared__ int nbrL[40];

  int tid = threadIdx.x;
  int qid0 = blockIdx.x * 2;
  if (tid < 128){
    int ql = tid >> 6, d = tid & 63;
    int qid = qid0 + ql;
    int node = ((qid >> 12) << 14) + ((qid & 4095) << 2);
    xdL[ql][d] = x[node * 64 + d];
  } else if (tid < 146){
    int t = tid - 128; int ql = t / 9, j = t - 9 * ql;
    int qid = qid0 + ql;
    int node = ((qid >> 12) << 14) + ((qid & 4095) << 2);
    lfL[ql][j] = lfr[node * 9 + j];
  } else if (tid < 186){
    int t = tid - 146; int ql = t / 20, j = t - 20 * ql;
    nbrL[t] = nbr[(qid0 + ql) * 20 + j];
  }
  __syncthreads();
  // gather x_src (coalesced 64-float rows)
  #pragma unroll 1
  for (int p = 0; p < 10; p++){
    int e = (tid >> 6) + (p << 2), d = tid & 63;
    xs[e][d] = x[nbrL[e] * 64 + d];
  }
  __syncthreads();
  // build h: [0..63]=x_dst, [64..79]=rel scalars, [80..127]=R_dst @ rel_vec
  {
    int d = tid & 127;
    int cls, kk = 0, aa = 0;
    if (d < 64) cls = 0;
    else { int dd = d - 64;
      if (dd < 16) cls = 1;
      else { cls = 2; int r = dd - 16; kk = (r * 21846) >> 16; aa = r - 3 * kk; } }
    #pragma unroll 1
    for (int p = 0; p < 20; p++){
      int e = (tid >> 7) + (p << 1);
      int ql = (e >= 20) ? 1 : 0;
      float v;
      if (cls == 0) v = xdL[ql][d];
      else if (cls == 1) v = xs[e][d - 64] - xdL[ql][d - 64];
      else {
        int base = 16 + 3 * kk;
        float u0 = xs[e][base]     - xdL[ql][base];
        float u1 = xs[e][base + 1] - xdL[ql][base + 1];
        float u2 = xs[e][base + 2] - xdL[ql][base + 2];
        v = lfL[ql][aa * 3] * u0 + lfL[ql][aa * 3 + 1] * u1 + lfL[ql][aa * 3 + 2] * u2;
      }
      h[e][d] = v;
    }
  }
  __syncthreads();
  int eg = tid >> 7, og = tid & 127;
  // layer 1
  {
    float acc1[20];
    float bv = b1[og];
    #pragma unroll
    for (int i = 0; i < 20; i++) acc1[i] = bv;
    for (int d0 = 0; d0 < 128; d0 += 4){
      float w0 = W1[(d0 + 0) * 128 + og];
      float w1 = W1[(d0 + 1) * 128 + og];
      float w2 = W1[(d0 + 2) * 128 + og];
      float w3 = W1[(d0 + 3) * 128 + og];
      #pragma unroll
      for (int i = 0; i < 20; i++){
        float4 hv = *(float4*)&h[eg * 20 + i][d0];
        acc1[i] += hv.x * w0 + hv.y * w1 + hv.z * w2 + hv.w * w3;
      }
    }
    #pragma unroll
    for (int i = 0; i < 20; i++) a1[eg * 20 + i][og] = fmaxf(acc1[i], 0.f);
  }
  __syncthreads();
  // layer 2 + max over edges
  {
    float acc2[20];
    #pragma unroll
    for (int i = 0; i < 20; i++) acc2[i] = 0.f;
    for (int d0 = 0; d0 < 128; d0 += 4){
      float w0 = W2[(d0 + 0) * 128 + og];
      float w1 = W2[(d0 + 1) * 128 + og];
      float w2 = W2[(d0 + 2) * 128 + og];
      float w3 = W2[(d0 + 3) * 128 + og];
      #pragma unroll
      for (int i = 0; i < 20; i++){
        float4 av = *(float4*)&a1[eg * 20 + i][d0];
        acc2[i] += av.x * w0 + av.y * w1 + av.z * w2 + av.w * w3;
      }
    }
    float m = -3.0e38f;
    #pragma unroll
    for (int i = 0; i < 20; i++) m = fmaxf(m, acc2[i]);
    m += b2[og];
    out[(qid0 + eg) * 128 + og] = m;
  }
}

// ---------------------------------------------------------------------------
// k_tail: pos[idx], batch[idx], lframes[idx] as fp32 at flat offsets.
// ---------------------------------------------------------------------------
__global__ __launch_bounds__(256) void k_tail(const float* __restrict__ pos,
    const float* __restrict__ lfr, float* __restrict__ out){
  int q = blockIdx.x * 256 + threadIdx.x;   // 0..16383
  int b = q >> 12;
  int node = (b << 14) + ((q & 4095) << 2);
  float* o_pos = out + 2097152;    // 16384*128
  float* o_bat = out + 2146304;    // + 16384*3
  float* o_lf  = out + 2162688;    // + 16384
  #pragma unroll
  for (int j = 0; j < 3; j++) o_pos[q * 3 + j] = pos[node * 3 + j];
  o_bat[q] = (float)b;
  #pragma unroll
  for (int j = 0; j < 9; j++) o_lf[q * 9 + j] = lfr[node * 9 + j];
}

extern "C" void kernel_launch(void* const* d_in, const int* in_sizes, int n_in,
                              void* d_out, int out_size, void* d_ws, size_t ws_size,
                              hipStream_t stream){
  const float* x   = (const float*)d_in[0];
  const float* pos = (const float*)d_in[1];
  const float* lfr = (const float*)d_in[2];
  // d_in[3] = batch (recomputed analytically)
  const float* W1  = (const float*)d_in[4];
  const float* b1  = (const float*)d_in[5];
  const float* W2  = (const float*)d_in[6];
  const float* b2  = (const float*)d_in[7];

  float* kfT = (float*)d_ws;                 // 68*65536 floats = 17.8 MB
  int*   nbr = (int*)d_ws + NBR_OFF;         // 16384*20 ints
  float* out = (float*)d_out;

  hipLaunchKernelGGL(k_prep, dim3(256),  dim3(256), 0, stream, x, pos, lfr, kfT);
  hipLaunchKernelGGL(k_knn,  dim3(256),  dim3(256), 0, stream, kfT, x, pos, lfr, nbr);
  hipLaunchKernelGGL(k_mlp,  dim3(8192), dim3(256), 0, stream, x, lfr, nbr, W1, b1, W2, b2, out);
  hipLaunchKernelGGL(k_tail, dim3(64),   dim3(256), 0, stream, pos, lfr, out);
}

// Round 5
// 1451.365 us; speedup vs baseline: 2.9550x; 1.2847x over previous
//
#include <hip/hip_runtime.h>
#include <hip/hip_bf16.h>

// Problem constants
#define NTOT 65536      // B*N
#define NB   16384      // N per batch
#define MB   4096       // M per batch (queries/batch)
#define NQ   16384      // total queries
#define KNN  20
#define CKEEP 32        // kept candidates for exact re-rank (margin over 20)
#define CAPB 224        // candidate buffer rows (headroom 128 over 96)
#define BPAD 65         // padded row width (64 queries + 1) -> bank varies with row
#define HEADROOM 96     // compact when cnt > HEADROOM
#define KFT_ROWS 68     // 67 dims + squared-norm row

// ws layout (floats): kfT[68][65536], then nbr int[NQ*KNN]
#define NBR_OFF (KFT_ROWS * NTOT)

// ---------------------------------------------------------------------------
// k_prep: per-node kf = [s(16), R^T v (48), pos(3)], plus |kf|^2, stored
// dim-major: kfT[d][node]  (coalesced across nodes for every d).
// ---------------------------------------------------------------------------
__global__ __launch_bounds__(256) void k_prep(const float* __restrict__ x,
        const float* __restrict__ pos, const float* __restrict__ lfr,
        float* __restrict__ kfT){
  int n = blockIdx.x * 256 + threadIdx.x;
  const float* xr = x + n * 64;
  float R[9];
  #pragma unroll
  for (int j = 0; j < 9; j++) R[j] = lfr[n * 9 + j];
  float c[67];
  #pragma unroll
  for (int i = 0; i < 16; i++) c[i] = xr[i];
  #pragma unroll
  for (int k = 0; k < 16; k++){
    float v0 = xr[16 + 3*k], v1 = xr[17 + 3*k], v2 = xr[18 + 3*k];
    #pragma unroll
    for (int a = 0; a < 3; a++)
      c[16 + 3*k + a] = R[a] * v0 + R[3 + a] * v1 + R[6 + a] * v2;  // R^T v
  }
  #pragma unroll
  for (int a = 0; a < 3; a++) c[64 + a] = pos[n * 3 + a];
  float sq = 0.f;
  #pragma unroll
  for (int d = 0; d < 67; d++) sq += c[d] * c[d];
  #pragma unroll
  for (int d = 0; d < 67; d++) kfT[d * NTOT + n] = c[d];
  kfT[67 * NTOT + n] = sq;
}

// ---------------------------------------------------------------------------
// k_knn: fused distance + streaming top-K.
// 512 threads/block (8 waves -> 2 waves/SIMD for latency hiding at 1 blk/CU).
// 64 queries/block, key tiles of 256, 4q x 8k register micro-tile.
// Candidates packed u32 = round(d2) upper-18-bits | key_idx(14b), stored
// TRANSPOSED buf[p][q] (padded stride 65 -> conflict-free scans).
// Compaction: block-uniform trigger (cnt>96), cooperative 8-lanes/query
// selection of best-32, tau = 32nd best. Final 32 re-ranked in fp64.
// ---------------------------------------------------------------------------
__device__ __forceinline__ void coop_compact(unsigned (*buf)[BPAD],
    unsigned (*srt)[BPAD], int* cnt, float* tau, int tid){
  int q = tid >> 3, s = tid & 7;
  int cn = cnt[q];
  #pragma unroll 1
  for (int r = 0; r < 32; r++){
    unsigned best = 0xFFFFFFFFu; int bj = -1;
    for (int j = s; j < cn; j += 8){
      unsigned v = buf[j][q];
      if (v < best){ best = v; bj = j; }
    }
    #pragma unroll
    for (int off = 1; off < 8; off <<= 1){
      unsigned ov = (unsigned)__shfl_xor((int)best, off, 64);
      int      oj = __shfl_xor(bj, off, 64);
      if (ov < best){ best = ov; bj = oj; }
    }
    if (bj >= 0 && s == (bj & 7)) buf[bj][q] = 0xFFFFFFFFu;  // extract
    if (s == 0) srt[r][q] = best;
    __syncthreads();
  }
  for (int r = s; r < 32; r += 8) buf[r][q] = srt[r][q];
  if (s == 0){ cnt[q] = 32; tau[q] = __uint_as_float(srt[31][q] & 0xFFFFC000u); }
  __syncthreads();
}

__global__ __launch_bounds__(512, 2) void k_knn(const float* __restrict__ kfT,
    const float* __restrict__ x, const float* __restrict__ pos,
    const float* __restrict__ lfr, int* __restrict__ nbr){
  __shared__ __attribute__((aligned(16))) float qsT[KFT_ROWS][64];  // 17408 B
  __shared__ __attribute__((aligned(16))) float ksT[KFT_ROWS][256]; // 69632 B (reused as fp64 re-rank scratch)
  __shared__ unsigned buf[CAPB][BPAD];                              // 58240 B
  __shared__ unsigned srt[32][BPAD];                                // 8320 B
  __shared__ int cnt[64];
  __shared__ float tau[64];
  __shared__ int flagS;

  int tid = threadIdx.x;
  int blk = blockIdx.x;
  // XCD-friendly swizzle: 2 consecutive-XCD slots per batch
  int b = (blk & 7) >> 1;
  int w = ((blk >> 3) << 1) | (blk & 1);   // 0..63 within batch
  int bbase = b << 14;                     // b*16384
  int q0 = w << 6;                         // within-batch query base (w*64)

  if (tid < 64){ cnt[tid] = 0; tau[tid] = 3.0e38f; }
  if (tid == 0) flagS = 0;
  // stage queries (node = bbase + 4*(q0+i)), rows 0..67
  for (int p = tid; p < KFT_ROWS * 64; p += 512){
    int d = p >> 6, i = p & 63;
    qsT[d][i] = kfT[d * NTOT + bbase + ((q0 + i) << 2)];
  }
  __syncthreads();

  int qg = tid >> 5, kg = tid & 31;   // qg 0..15 (4 queries each), kg 0..31 (8 keys each)
  float qsq[4];
  #pragma unroll
  for (int i = 0; i < 4; i++) qsq[i] = qsT[67][(qg << 2) + i];

  for (int tile = 0; tile < 64; ++tile){
    __syncthreads();   // previous tile's reads of ksT complete
    int kbase = tile << 8;
    // stage 256 keys dim-major: 68*64 float4s, coalesced global, conflict-free LDS
    for (int p = tid; p < KFT_ROWS * 64; p += 512){
      int d = p >> 6, k4 = (p & 63) << 2;
      *(float4*)&ksT[d][k4] = *(const float4*)&kfT[d * NTOT + bbase + kbase + k4];
    }
    __syncthreads();

    float acc[4][8];
    #pragma unroll
    for (int i = 0; i < 4; i++)
      #pragma unroll
      for (int j = 0; j < 8; j++) acc[i][j] = 0.f;

    for (int d = 0; d < 67; ++d){
      float4 ka = *(float4*)&ksT[d][kg << 2];
      float4 kb = *(float4*)&ksT[d][128 + (kg << 2)];
      float4 qa = *(float4*)&qsT[d][qg << 2];
      float qv[4] = {qa.x, qa.y, qa.z, qa.w};
      float kv[8] = {ka.x, ka.y, ka.z, ka.w, kb.x, kb.y, kb.z, kb.w};
      #pragma unroll
      for (int i = 0; i < 4; i++)
        #pragma unroll
        for (int j = 0; j < 8; j++)
          acc[i][j] += qv[i] * kv[j];
    }

    float ksq[8];
    #pragma unroll
    for (int j = 0; j < 4; j++){
      ksq[j]     = ksT[67][(kg << 2) + j];
      ksq[4 + j] = ksT[67][128 + (kg << 2) + j];
    }

    // phase A: keys [kbase+4kg .. +3]
    #pragma unroll
    for (int i = 0; i < 4; i++){
      int q = (qg << 2) + i;
      float tq = tau[q];
      #pragma unroll
      for (int j = 0; j < 4; j++){
        float d2 = fmaxf(qsq[i] + ksq[j] - 2.f * acc[i][j], 0.f);
        if (d2 < tq){
          int p = atomicAdd(&cnt[q], 1);
          buf[p][q] = ((__float_as_uint(d2) + 0x2000u) & 0xFFFFC000u) | (unsigned)(kbase + (kg << 2) + j);
        }
      }
    }
    __syncthreads();
    if (tid < 64 && cnt[tid] > HEADROOM) flagS = 1;
    __syncthreads();
    if (flagS){
      coop_compact(buf, srt, cnt, tau, tid);
      if (tid == 0) flagS = 0;
    }
    // phase B: keys [kbase+128+4kg .. +3]
    #pragma unroll
    for (int i = 0; i < 4; i++){
      int q = (qg << 2) + i;
      float tq = tau[q];
      #pragma unroll
      for (int j = 0; j < 4; j++){
        float d2 = fmaxf(qsq[i] + ksq[4 + j] - 2.f * acc[i][4 + j], 0.f);
        if (d2 < tq){
          int p = atomicAdd(&cnt[q], 1);
          buf[p][q] = ((__float_as_uint(d2) + 0x2000u) & 0xFFFFC000u) | (unsigned)(kbase + 128 + (kg << 2) + j);
        }
      }
    }
    __syncthreads();
    if (tid < 64 && cnt[tid] > HEADROOM) flagS = 1;
    __syncthreads();
    if (flagS){
      coop_compact(buf, srt, cnt, tau, tid);
      if (tid == 0) flagS = 0;
    }
  }
  __syncthreads();
  coop_compact(buf, srt, cnt, tau, tid);   // final: buf rows 0..31 = best-32
  __syncthreads();

  // ---- exact fp64 re-rank of the 32 survivors (kf rebuilt from raw inputs) ----
  // LDS overlay on ksT: qkf double[64][67] | rrD double[64][32] | rrI int[64][32]
  double* qkf = (double*)&ksT[0][0];
  double* rrD = qkf + 64 * 67;
  int*    rrI = (int*)(rrD + 64 * CKEEP);

  {  // rebuild query kf in fp64
    int t8 = tid & 7, q = tid >> 3;
    int node = bbase + ((q0 + q) << 2);
    const float* xr = x + node * 64;
    for (int dd = t8; dd < 67; dd += 8){
      double val;
      if (dd < 16) val = (double)xr[dd];
      else if (dd < 64){
        int r = dd - 16; int k = r / 3; int a = r - 3 * k;
        val = (double)lfr[node*9 + a]     * (double)xr[16 + 3*k]
            + (double)lfr[node*9 + 3 + a] * (double)xr[17 + 3*k]
            + (double)lfr[node*9 + 6 + a] * (double)xr[18 + 3*k];
      } else val = (double)pos[node*3 + (dd - 64)];
      qkf[q * 67 + dd] = val;
    }
  }
  __syncthreads();
  {  // candidate d2 in fp64
    int t8 = tid & 7, q = tid >> 3;
    for (int j = t8; j < CKEEP; j += 8){
      int idx = (int)(buf[j][q] & 0x3FFFu);
      int node = bbase + idx;
      const float* xr = x + node * 64;
      double R[9];
      #pragma unroll
      for (int t = 0; t < 9; t++) R[t] = (double)lfr[node * 9 + t];
      double d2 = 0.0;
      #pragma unroll
      for (int dd = 0; dd < 16; dd++){ double t = (double)xr[dd] - qkf[q*67 + dd]; d2 += t * t; }
      #pragma unroll
      for (int k = 0; k < 16; k++){
        double v0 = xr[16 + 3*k], v1 = xr[17 + 3*k], v2 = xr[18 + 3*k];
        #pragma unroll
        for (int a = 0; a < 3; a++){
          double val = R[a] * v0 + R[3 + a] * v1 + R[6 + a] * v2;
          double t = val - qkf[q*67 + 16 + 3*k + a]; d2 += t * t;
        }
      }
      #pragma unroll
      for (int a = 0; a < 3; a++){ double t = (double)pos[node*3 + a] - qkf[q*67 + 64 + a]; d2 += t * t; }
      rrD[q * CKEEP + j] = d2; rrI[q * CKEEP + j] = idx;
    }
  }
  __syncthreads();
  if (tid < 64){
    int qq = tid;
    int qid = (b << 12) + q0 + qq;   // global query id
    #pragma unroll 1
    for (int s = 0; s < KNN; s++){
      double best = rrD[qq * CKEEP + s]; int bi = s;
      for (int t = s + 1; t < CKEEP; t++){
        double v = rrD[qq * CKEEP + t]; if (v < best){ best = v; bi = t; }
      }
      double tv = rrD[qq * CKEEP + bi]; rrD[qq * CKEEP + bi] = rrD[qq * CKEEP + s]; rrD[qq * CKEEP + s] = tv;
      int ti = rrI[qq * CKEEP + bi]; rrI[qq * CKEEP + bi] = rrI[qq * CKEEP + s]; rrI[qq * CKEEP + s] = ti;
      nbr[qid * KNN + s] = bbase + rrI[qq * CKEEP + s];
    }
  }
}

// ---------------------------------------------------------------------------
// k_mlp: 2 queries/block (40 edges). Gather x_src, build h=[x_dst, rel_local],
// relu(h@W1+b1)@W2, max over edges, +b2, fp32 store.
// Micro-tile: 20 edges x 1 output per thread; h/a1 LDS reads are wave-broadcast.
// ---------------------------------------------------------------------------
__global__ __launch_bounds__(256) void k_mlp(const float* __restrict__ x,
    const float* __restrict__ lfr, const int* __restrict__ nbr,
    const float* __restrict__ W1, const float* __restrict__ b1,
    const float* __restrict__ W2, const float* __restrict__ b2,
    float* __restrict__ out){
  __shared__ float xs[40][64];
  __shared__ float h[40][128];
  __shared__ float a1[40][128];
  __shared__ float xdL[2][64];
  __shared__ float lfL[2][9];
  __shared__ int nbrL[40];

  int tid = threadIdx.x;
  int qid0 = blockIdx.x * 2;
  if (tid < 128){
    int ql = tid >> 6, d = tid & 63;
    int qid = qid0 + ql;
    int node = ((qid >> 12) << 14) + ((qid & 4095) << 2);
    xdL[ql][d] = x[node * 64 + d];
  } else if (tid < 146){
    int t = tid - 128; int ql = t / 9, j = t - 9 * ql;
    int qid = qid0 + ql;
    int node = ((qid >> 12) << 14) + ((qid & 4095) << 2);
    lfL[ql][j] = lfr[node * 9 + j];
  } else if (tid < 186){
    int t = tid - 146; int ql = t / 20, j = t - 20 * ql;
    nbrL[t] = nbr[(qid0 + ql) * 20 + j];
  }
  __syncthreads();
  // gather x_src (coalesced 64-float rows)
  #pragma unroll 1
  for (int p = 0; p < 10; p++){
    int e = (tid >> 6) + (p << 2), d = tid & 63;
    xs[e][d] = x[nbrL[e] * 64 + d];
  }
  __syncthreads();
  // build h: [0..63]=x_dst, [64..79]=rel scalars, [80..127]=R_dst @ rel_vec
  {
    int d = tid & 127;
    int cls, kk = 0, aa = 0;
    if (d < 64) cls = 0;
    else { int dd = d - 64;
      if (dd < 16) cls = 1;
      else { cls = 2; int r = dd - 16; kk = (r * 21846) >> 16; aa = r - 3 * kk; } }
    #pragma unroll 1
    for (int p = 0; p < 20; p++){
      int e = (tid >> 7) + (p << 1);
      int ql = (e >= 20) ? 1 : 0;
      float v;
      if (cls == 0) v = xdL[ql][d];
      else if (cls == 1) v = xs[e][d - 64] - xdL[ql][d - 64];
      else {
        int base = 16 + 3 * kk;
        float u0 = xs[e][base]     - xdL[ql][base];
        float u1 = xs[e][base + 1] - xdL[ql][base + 1];
        float u2 = xs[e][base + 2] - xdL[ql][base + 2];
        v = lfL[ql][aa * 3] * u0 + lfL[ql][aa * 3 + 1] * u1 + lfL[ql][aa * 3 + 2] * u2;
      }
      h[e][d] = v;
    }
  }
  __syncthreads();
  int eg = tid >> 7, og = tid & 127;
  // layer 1
  {
    float acc1[20];
    float bv = b1[og];
    #pragma unroll
    for (int i = 0; i < 20; i++) acc1[i] = bv;
    for (int d0 = 0; d0 < 128; d0 += 4){
      float w0 = W1[(d0 + 0) * 128 + og];
      float w1 = W1[(d0 + 1) * 128 + og];
      float w2 = W1[(d0 + 2) * 128 + og];
      float w3 = W1[(d0 + 3) * 128 + og];
      #pragma unroll
      for (int i = 0; i < 20; i++){
        float4 hv = *(float4*)&h[eg * 20 + i][d0];
        acc1[i] += hv.x * w0 + hv.y * w1 + hv.z * w2 + hv.w * w3;
      }
    }
    #pragma unroll
    for (int i = 0; i < 20; i++) a1[eg * 20 + i][og] = fmaxf(acc1[i], 0.f);
  }
  __syncthreads();
  // layer 2 + max over edges
  {
    float acc2[20];
    #pragma unroll
    for (int i = 0; i < 20; i++) acc2[i] = 0.f;
    for (int d0 = 0; d0 < 128; d0 += 4){
      float w0 = W2[(d0 + 0) * 128 + og];
      float w1 = W2[(d0 + 1) * 128 + og];
      float w2 = W2[(d0 + 2) * 128 + og];
      float w3 = W2[(d0 + 3) * 128 + og];
      #pragma unroll
      for (int i = 0; i < 20; i++){
        float4 av = *(float4*)&a1[eg * 20 + i][d0];
        acc2[i] += av.x * w0 + av.y * w1 + av.z * w2 + av.w * w3;
      }
    }
    float m = -3.0e38f;
    #pragma unroll
    for (int i = 0; i < 20; i++) m = fmaxf(m, acc2[i]);
    m += b2[og];
    out[(qid0 + eg) * 128 + og] = m;
  }
}

// ---------------------------------------------------------------------------
// k_tail: pos[idx], batch[idx], lframes[idx] as fp32 at flat offsets.
// ---------------------------------------------------------------------------
__global__ __launch_bounds__(256) void k_tail(const float* __restrict__ pos,
    const float* __restrict__ lfr, float* __restrict__ out){
  int q = blockIdx.x * 256 + threadIdx.x;   // 0..16383
  int b = q >> 12;
  int node = (b << 14) + ((q & 4095) << 2);
  float* o_pos = out + 2097152;    // 16384*128
  float* o_bat = out + 2146304;    // + 16384*3
  float* o_lf  = out + 2162688;    // + 16384
  #pragma unroll
  for (int j = 0; j < 3; j++) o_pos[q * 3 + j] = pos[node * 3 + j];
  o_bat[q] = (float)b;
  #pragma unroll
  for (int j = 0; j < 9; j++) o_lf[q * 9 + j] = lfr[node * 9 + j];
}

extern "C" void kernel_launch(void* const* d_in, const int* in_sizes, int n_in,
                              void* d_out, int out_size, void* d_ws, size_t ws_size,
                              hipStream_t stream){
  const float* x   = (const float*)d_in[0];
  const float* pos = (const float*)d_in[1];
  const float* lfr = (const float*)d_in[2];
  // d_in[3] = batch (recomputed analytically)
  const float* W1  = (const float*)d_in[4];
  const float* b1  = (const float*)d_in[5];
  const float* W2  = (const float*)d_in[6];
  const float* b2  = (const float*)d_in[7];

  float* kfT = (float*)d_ws;                 // 68*65536 floats = 17.8 MB
  int*   nbr = (int*)d_ws + NBR_OFF;         // 16384*20 ints
  float* out = (float*)d_out;

  hipLaunchKernelGGL(k_prep, dim3(256),  dim3(256), 0, stream, x, pos, lfr, kfT);
  hipLaunchKernelGGL(k_knn,  dim3(256),  dim3(512), 0, stream, kfT, x, pos, lfr, nbr);
  hipLaunchKernelGGL(k_mlp,  dim3(8192), dim3(256), 0, stream, x, lfr, nbr, W1, b1, W2, b2, out);
  hipLaunchKernelGGL(k_tail, dim3(64),   dim3(256), 0, stream, pos, lfr, out);
}

// Round 6
// 1115.778 us; speedup vs baseline: 3.8438x; 1.3008x over previous
//
#include <hip/hip_runtime.h>
#include <hip/hip_bf16.h>

// Problem constants
#define NTOT 65536      // B*N
#define NB   16384      // N per batch
#define MB   4096       // M per batch (queries/batch)
#define NQ   16384      // total queries
#define KNN  20
#define CKEEP 32        // kept candidates for exact re-rank (margin over 20)
#define CAPB 224        // candidate buffer rows (headroom 128 over 96)
#define BPAD 65         // padded row width (64 queries + 1)
#define HEADROOM 96     // compact when cnt > HEADROOM
#define KROW 104        // bf16 kf row stride (67 dims + zero pad; 52 dwords = bank-friendly)

typedef __attribute__((ext_vector_type(4))) float f32x4;
typedef __attribute__((ext_vector_type(8))) short s16x8;

// ws layout (bytes): kfB bf16[65536][104] = 13631488 | normB f32[65536] | nbr i32[NQ*KNN]
#define WS_NORM 13631488
#define WS_NBR  13893632

// k_knn LDS map (bytes)
#define SMEM_KSB 0          // ushort ksB[256][104]   53248
#define SMEM_KSQ 53248      // float ksq[256]          1024
#define SMEM_SRT 54272      // unsigned srt[32][65]    8320
#define SMEM_BUF 62592      // unsigned buf[224][65]  58240
#define SMEM_CNT 120832     // int cnt[64]
#define SMEM_TAU 121088     // float tau[64]
#define SMEM_FLG 121344     // int flag
#define SMEM_SZ  121360
// re-rank overlay on [0, 58880) (ksB/ksq/srt region; buf untouched):
//   qkf double[64][67] @0 (34304) | rrD double[64][32] @34304 (16384) | rrI int[64][32] @50688 (8192)

__device__ __forceinline__ unsigned short f2bf_rne(float v){
  unsigned u = __float_as_uint(v);
  return (unsigned short)((u + 0x7FFFu + ((u >> 16) & 1u)) >> 16);
}

// ---------------------------------------------------------------------------
// k_prep: per-node kf = [s(16), R^T v (48), pos(3)] -> bf16 key-major rows
// (padded to 104) + fp32 squared norm.
// ---------------------------------------------------------------------------
__global__ __launch_bounds__(256) void k_prep(const float* __restrict__ x,
        const float* __restrict__ pos, const float* __restrict__ lfr,
        unsigned short* __restrict__ kfB, float* __restrict__ normB){
  int n = blockIdx.x * 256 + threadIdx.x;
  const float* xr = x + n * 64;
  float R[9];
  #pragma unroll
  for (int j = 0; j < 9; j++) R[j] = lfr[n * 9 + j];
  float c[67];
  #pragma unroll
  for (int i = 0; i < 16; i++) c[i] = xr[i];
  #pragma unroll
  for (int k = 0; k < 16; k++){
    float v0 = xr[16 + 3*k], v1 = xr[17 + 3*k], v2 = xr[18 + 3*k];
    #pragma unroll
    for (int a = 0; a < 3; a++)
      c[16 + 3*k + a] = R[a] * v0 + R[3 + a] * v1 + R[6 + a] * v2;  // R^T v
  }
  #pragma unroll
  for (int a = 0; a < 3; a++) c[64 + a] = pos[n * 3 + a];
  float sq = 0.f;
  #pragma unroll
  for (int d = 0; d < 67; d++) sq += c[d] * c[d];
  __attribute__((aligned(16))) unsigned short row[KROW];
  #pragma unroll
  for (int d = 0; d < 67; d++) row[d] = f2bf_rne(c[d]);
  #pragma unroll
  for (int d = 67; d < KROW; d++) row[d] = 0;
  uint4* dst = (uint4*)(kfB + (size_t)n * KROW);
  const uint4* s4 = (const uint4*)row;
  #pragma unroll
  for (int i = 0; i < 13; i++) dst[i] = s4[i];
  normB[n] = sq;
}

// ---------------------------------------------------------------------------
// coop_compact: cooperative best-32 selection (8 lanes/query), tau = 32nd best.
// ---------------------------------------------------------------------------
__device__ __forceinline__ void coop_compact(unsigned (*buf)[BPAD],
    unsigned (*srt)[BPAD], int* cnt, float* tau, int tid){
  int q = tid >> 3, s = tid & 7;
  int cn = cnt[q];
  #pragma unroll 1
  for (int r = 0; r < 32; r++){
    unsigned best = 0xFFFFFFFFu; int bj = -1;
    for (int j = s; j < cn; j += 8){
      unsigned v = buf[j][q];
      if (v < best){ best = v; bj = j; }
    }
    #pragma unroll
    for (int off = 1; off < 8; off <<= 1){
      unsigned ov = (unsigned)__shfl_xor((int)best, off, 64);
      int      oj = __shfl_xor(bj, off, 64);
      if (ov < best){ best = ov; bj = oj; }
    }
    if (bj >= 0 && s == (bj & 7)) buf[bj][q] = 0xFFFFFFFFu;  // extract
    if (s == 0) srt[r][q] = best;
    __syncthreads();
  }
  for (int r = s; r < 32; r += 8) buf[r][q] = srt[r][q];
  if (s == 0){ cnt[q] = 32; tau[q] = __uint_as_float(srt[31][q] & 0xFFFFC000u); }
  __syncthreads();
}

// ---------------------------------------------------------------------------
// k_knn: MFMA bf16 coarse distances + streaming top-K + exact fp64 re-rank.
// 512 thr (8 waves). 64 queries/block, key tiles of 256.
// Wave w: mt-pair p=w>>2 (2 m-tiles), nt-group g=w&3 (4 n-tiles).
// Per tile: 24 mfma_f32_16x16x32_bf16 + 12 ds_read_b128 per wave.
// ---------------------------------------------------------------------------
__global__ __launch_bounds__(512, 2) void k_knn(
    const unsigned short* __restrict__ kfB, const float* __restrict__ normB,
    const float* __restrict__ x, const float* __restrict__ pos,
    const float* __restrict__ lfr, int* __restrict__ nbr){
  __shared__ __attribute__((aligned(16))) char smem[SMEM_SZ];
  unsigned short* ksB = (unsigned short*)(smem + SMEM_KSB);
  float* ksq = (float*)(smem + SMEM_KSQ);
  unsigned (*srt)[BPAD] = (unsigned (*)[BPAD])(smem + SMEM_SRT);
  unsigned (*buf)[BPAD] = (unsigned (*)[BPAD])(smem + SMEM_BUF);
  int* cnt = (int*)(smem + SMEM_CNT);
  float* tau = (float*)(smem + SMEM_TAU);
  int* flagS = (int*)(smem + SMEM_FLG);

  int tid = threadIdx.x;
  int blk = blockIdx.x;
  int b = (blk & 7) >> 1;
  int w = ((blk >> 3) << 1) | (blk & 1);   // 0..63 within batch
  int bbase = b << 14;
  int q0 = w << 6;

  if (tid < 64){ cnt[tid] = 0; tau[tid] = 3.0e38f; }
  if (tid == 0) *flagS = 0;

  int lane = tid & 63;
  int wv = tid >> 6;             // wave 0..7
  int p = wv >> 2;               // mt pair 0..1
  int g = wv & 3;                // nt group 0..3
  int l15 = lane & 15, quad = lane >> 4;

  // A fragments (queries) + query norms, once per block, from global
  s16x8 afr[2][3];
  float qsqv[2][4];
  #pragma unroll
  for (int mtl = 0; mtl < 2; mtl++){
    int mt = p * 2 + mtl;
    int nodeA = bbase + ((q0 + mt * 16 + l15) << 2);
    #pragma unroll
    for (int ks = 0; ks < 3; ks++)
      afr[mtl][ks] = *(const s16x8*)(kfB + (size_t)nodeA * KROW + ks * 32 + quad * 8);
    #pragma unroll
    for (int r = 0; r < 4; r++){
      int nodeQ = bbase + ((q0 + mt * 16 + quad * 4 + r) << 2);
      qsqv[mtl][r] = normB[nodeQ];
    }
  }
  __syncthreads();

  for (int tile = 0; tile < 64; ++tile){
    __syncthreads();
    int kbase = tile << 8;
    // stage 256 key rows (bf16, KROW) + 256 norms: flat coalesced copy
    {
      const uint4* src = (const uint4*)(kfB + (size_t)(bbase + kbase) * KROW);
      uint4* dst = (uint4*)ksB;
      #pragma unroll 1
      for (int i = tid; i < 256 * KROW / 8; i += 512) dst[i] = src[i];
      if (tid < 256) ksq[tid] = normB[bbase + kbase + tid];
    }
    __syncthreads();

    float ksqv[4];
    #pragma unroll
    for (int j = 0; j < 4; j++) ksqv[j] = ksq[(g * 4 + j) * 16 + l15];

    f32x4 acc[2][4];
    #pragma unroll
    for (int mtl = 0; mtl < 2; mtl++)
      #pragma unroll
      for (int j = 0; j < 4; j++) acc[mtl][j] = (f32x4){0.f, 0.f, 0.f, 0.f};

    #pragma unroll
    for (int ks = 0; ks < 3; ks++){
      s16x8 bfr[4];
      #pragma unroll
      for (int j = 0; j < 4; j++){
        int n = (g * 4 + j) * 16 + l15;
        bfr[j] = *(const s16x8*)(ksB + n * KROW + ks * 32 + quad * 8);
      }
      #pragma unroll
      for (int mtl = 0; mtl < 2; mtl++)
        #pragma unroll
        for (int j = 0; j < 4; j++)
          acc[mtl][j] = __builtin_amdgcn_mfma_f32_16x16x32_bf16(
              afr[mtl][ks], bfr[j], acc[mtl][j], 0, 0, 0);
    }

    // epilogue in two 128-key phases (capacity invariant: 96+128 <= 224)
    #pragma unroll
    for (int ph = 0; ph < 2; ph++){
      #pragma unroll
      for (int mtl = 0; mtl < 2; mtl++){
        #pragma unroll
        for (int j2 = 0; j2 < 2; j2++){
          int j = ph * 2 + j2;
          int kidx = kbase + (g * 4 + j) * 16 + l15;
          #pragma unroll
          for (int r = 0; r < 4; r++){
            int q = (p * 2 + mtl) * 16 + quad * 4 + r;
            float d2 = fmaxf(qsqv[mtl][r] + ksqv[j] - 2.f * acc[mtl][j][r], 0.f);
            if (d2 < tau[q]){
              int pp = atomicAdd(&cnt[q], 1);
              buf[pp][q] = ((__float_as_uint(d2) + 0x2000u) & 0xFFFFC000u) | (unsigned)kidx;
            }
          }
        }
      }
      __syncthreads();
      if (tid < 64 && cnt[tid] > HEADROOM) *flagS = 1;
      __syncthreads();
      if (*flagS){
        coop_compact(buf, srt, cnt, tau, tid);
        if (tid == 0) *flagS = 0;
      }
    }
  }
  __syncthreads();
  coop_compact(buf, srt, cnt, tau, tid);   // final: buf rows 0..31 = best-32
  __syncthreads();

  // ---- exact fp64 re-rank of the 32 survivors (kf rebuilt from raw inputs) ----
  double* qkf = (double*)(smem);
  double* rrD = (double*)(smem + 34304);
  int*    rrI = (int*)(smem + 50688);

  {  // rebuild query kf in fp64
    int t8 = tid & 7, q = tid >> 3;
    int node = bbase + ((q0 + q) << 2);
    const float* xr = x + node * 64;
    for (int dd = t8; dd < 67; dd += 8){
      double val;
      if (dd < 16) val = (double)xr[dd];
      else if (dd < 64){
        int r = dd - 16; int k = r / 3; int a = r - 3 * k;
        val = (double)lfr[node*9 + a]     * (double)xr[16 + 3*k]
            + (double)lfr[node*9 + 3 + a] * (double)xr[17 + 3*k]
            + (double)lfr[node*9 + 6 + a] * (double)xr[18 + 3*k];
      } else val = (double)pos[node*3 + (dd - 64)];
      qkf[q * 67 + dd] = val;
    }
  }
  __syncthreads();
  {  // candidate d2 in fp64
    int t8 = tid & 7, q = tid >> 3;
    for (int j = t8; j < CKEEP; j += 8){
      int idx = (int)(buf[j][q] & 0x3FFFu);
      int node = bbase + idx;
      const float* xr = x + node * 64;
      double R[9];
      #pragma unroll
      for (int t = 0; t < 9; t++) R[t] = (double)lfr[node * 9 + t];
      double d2 = 0.0;
      #pragma unroll
      for (int dd = 0; dd < 16; dd++){ double t = (double)xr[dd] - qkf[q*67 + dd]; d2 += t * t; }
      #pragma unroll
      for (int k = 0; k < 16; k++){
        double v0 = xr[16 + 3*k], v1 = xr[17 + 3*k], v2 = xr[18 + 3*k];
        #pragma unroll
        for (int a = 0; a < 3; a++){
          double val = R[a] * v0 + R[3 + a] * v1 + R[6 + a] * v2;
          double t = val - qkf[q*67 + 16 + 3*k + a]; d2 += t * t;
        }
      }
      #pragma unroll
      for (int a = 0; a < 3; a++){ double t = (double)pos[node*3 + a] - qkf[q*67 + 64 + a]; d2 += t * t; }
      rrD[q * CKEEP + j] = d2; rrI[q * CKEEP + j] = idx;
    }
  }
  __syncthreads();
  if (tid < 64){
    int qq = tid;
    int qid = (b << 12) + q0 + qq;
    #pragma unroll 1
    for (int s = 0; s < KNN; s++){
      double best = rrD[qq * CKEEP + s]; int bi = s;
      for (int t = s + 1; t < CKEEP; t++){
        double v = rrD[qq * CKEEP + t]; if (v < best){ best = v; bi = t; }
      }
      double tv = rrD[qq * CKEEP + bi]; rrD[qq * CKEEP + bi] = rrD[qq * CKEEP + s]; rrD[qq * CKEEP + s] = tv;
      int ti = rrI[qq * CKEEP + bi]; rrI[qq * CKEEP + bi] = rrI[qq * CKEEP + s]; rrI[qq * CKEEP + s] = ti;
      nbr[qid * KNN + s] = bbase + rrI[qq * CKEEP + s];
    }
  }
}

// ---------------------------------------------------------------------------
// k_mlp: 2 queries/block (40 edges). Gather x_src, build h=[x_dst, rel_local],
// relu(h@W1+b1)@W2, max over edges, +b2, fp32 store.
// ---------------------------------------------------------------------------
__global__ __launch_bounds__(256) void k_mlp(const float* __restrict__ x,
    const float* __restrict__ lfr, const int* __restrict__ nbr,
    const float* __restrict__ W1, const float* __restrict__ b1,
    const float* __restrict__ W2, const float* __restrict__ b2,
    float* __restrict__ out){
  __shared__ float xs[40][64];
  __shared__ float h[40][128];
  __shared__ float a1[40][128];
  __shared__ float xdL[2][64];
  __shared__ float lfL[2][9];
  __shared__ int nbrL[40];

  int tid = threadIdx.x;
  int qid0 = blockIdx.x * 2;
  if (tid < 128){
    int ql = tid >> 6, d = tid & 63;
    int qid = qid0 + ql;
    int node = ((qid >> 12) << 14) + ((qid & 4095) << 2);
    xdL[ql][d] = x[node * 64 + d];
  } else if (tid < 146){
    int t = tid - 128; int ql = t / 9, j = t - 9 * ql;
    int qid = qid0 + ql;
    int node = ((qid >> 12) << 14) + ((qid & 4095) << 2);
    lfL[ql][j] = lfr[node * 9 + j];
  } else if (tid < 186){
    int t = tid - 146; int ql = t / 20, j = t - 20 * ql;
    nbrL[t] = nbr[(qid0 + ql) * 20 + j];
  }
  __syncthreads();
  #pragma unroll 1
  for (int p = 0; p < 10; p++){
    int e = (tid >> 6) + (p << 2), d = tid & 63;
    xs[e][d] = x[nbrL[e] * 64 + d];
  }
  __syncthreads();
  {
    int d = tid & 127;
    int cls, kk = 0, aa = 0;
    if (d < 64) cls = 0;
    else { int dd = d - 64;
      if (dd < 16) cls = 1;
      else { cls = 2; int r = dd - 16; kk = (r * 21846) >> 16; aa = r - 3 * kk; } }
    #pragma unroll 1
    for (int p = 0; p < 20; p++){
      int e = (tid >> 7) + (p << 1);
      int ql = (e >= 20) ? 1 : 0;
      float v;
      if (cls == 0) v = xdL[ql][d];
      else if (cls == 1) v = xs[e][d - 64] - xdL[ql][d - 64];
      else {
        int base = 16 + 3 * kk;
        float u0 = xs[e][base]     - xdL[ql][base];
        float u1 = xs[e][base + 1] - xdL[ql][base + 1];
        float u2 = xs[e][base + 2] - xdL[ql][base + 2];
        v = lfL[ql][aa * 3] * u0 + lfL[ql][aa * 3 + 1] * u1 + lfL[ql][aa * 3 + 2] * u2;
      }
      h[e][d] = v;
    }
  }
  __syncthreads();
  int eg = tid >> 7, og = tid & 127;
  {
    float acc1[20];
    float bv = b1[og];
    #pragma unroll
    for (int i = 0; i < 20; i++) acc1[i] = bv;
    for (int d0 = 0; d0 < 128; d0 += 4){
      float w0 = W1[(d0 + 0) * 128 + og];
      float w1 = W1[(d0 + 1) * 128 + og];
      float w2 = W1[(d0 + 2) * 128 + og];
      float w3 = W1[(d0 + 3) * 128 + og];
      #pragma unroll
      for (int i = 0; i < 20; i++){
        float4 hv = *(float4*)&h[eg * 20 + i][d0];
        acc1[i] += hv.x * w0 + hv.y * w1 + hv.z * w2 + hv.w * w3;
      }
    }
    #pragma unroll
    for (int i = 0; i < 20; i++) a1[eg * 20 + i][og] = fmaxf(acc1[i], 0.f);
  }
  __syncthreads();
  {
    float acc2[20];
    #pragma unroll
    for (int i = 0; i < 20; i++) acc2[i] = 0.f;
    for (int d0 = 0; d0 < 128; d0 += 4){
      float w0 = W2[(d0 + 0) * 128 + og];
      float w1 = W2[(d0 + 1) * 128 + og];
      float w2 = W2[(d0 + 2) * 128 + og];
      float w3 = W2[(d0 + 3) * 128 + og];
      #pragma unroll
      for (int i = 0; i < 20; i++){
        float4 av = *(float4*)&a1[eg * 20 + i][d0];
        acc2[i] += av.x * w0 + av.y * w1 + av.z * w2 + av.w * w3;
      }
    }
    float m = -3.0e38f;
    #pragma unroll
    for (int i = 0; i < 20; i++) m = fmaxf(m, acc2[i]);
    m += b2[og];
    out[(qid0 + eg) * 128 + og] = m;
  }
}

// ---------------------------------------------------------------------------
// k_tail: pos[idx], batch[idx], lframes[idx] as fp32 at flat offsets.
// ---------------------------------------------------------------------------
__global__ __launch_bounds__(256) void k_tail(const float* __restrict__ pos,
    const float* __restrict__ lfr, float* __restrict__ out){
  int q = blockIdx.x * 256 + threadIdx.x;   // 0..16383
  int b = q >> 12;
  int node = (b << 14) + ((q & 4095) << 2);
  float* o_pos = out + 2097152;    // 16384*128
  float* o_bat = out + 2146304;    // + 16384*3
  float* o_lf  = out + 2162688;    // + 16384
  #pragma unroll
  for (int j = 0; j < 3; j++) o_pos[q * 3 + j] = pos[node * 3 + j];
  o_bat[q] = (float)b;
  #pragma unroll
  for (int j = 0; j < 9; j++) o_lf[q * 9 + j] = lfr[node * 9 + j];
}

extern "C" void kernel_launch(void* const* d_in, const int* in_sizes, int n_in,
                              void* d_out, int out_size, void* d_ws, size_t ws_size,
                              hipStream_t stream){
  const float* x   = (const float*)d_in[0];
  const float* pos = (const float*)d_in[1];
  const float* lfr = (const float*)d_in[2];
  // d_in[3] = batch (recomputed analytically)
  const float* W1  = (const float*)d_in[4];
  const float* b1  = (const float*)d_in[5];
  const float* W2  = (const float*)d_in[6];
  const float* b2  = (const float*)d_in[7];

  unsigned short* kfB = (unsigned short*)d_ws;
  float* normB = (float*)((char*)d_ws + WS_NORM);
  int*   nbr   = (int*)((char*)d_ws + WS_NBR);
  float* out = (float*)d_out;

  hipLaunchKernelGGL(k_prep, dim3(256),  dim3(256), 0, stream, x, pos, lfr, kfB, normB);
  hipLaunchKernelGGL(k_knn,  dim3(256),  dim3(512), 0, stream, kfB, normB, x, pos, lfr, nbr);
  hipLaunchKernelGGL(k_mlp,  dim3(8192), dim3(256), 0, stream, x, lfr, nbr, W1, b1, W2, b2, out);
  hipLaunchKernelGGL(k_tail, dim3(64),   dim3(256), 0, stream, pos, lfr, out);
}